// Round 2
// baseline (4351.360 us; speedup 1.0000x reference)
//
#include <hip/hip_runtime.h>

namespace {
constexpr int NB = 16;    // batch
constexpr int NP = 50;    // P nodes
constexpr int NM = 512;   // M
constexpr int NN = 1024;  // N
constexpr int NK = 20;    // scan steps
constexpr long ASZ = (long)NP * NM * NN;   // 26,214,400
constexpr long YSZ = (long)NB * NP * NN;   // 819,200
}

__device__ __forceinline__ float lrelu(float x){ return x > 0.f ? x : 0.01f*x; }
__device__ __forceinline__ float bfu(unsigned short x){
  unsigned v = ((unsigned)x) << 16;
  return __builtin_bit_cast(float, v);
}
__device__ __forceinline__ unsigned short f2bf(float f){   // RNE f32->bf16
  unsigned u = __builtin_bit_cast(unsigned, f);
  u += 0x7fffu + ((u >> 16) & 1u);
  return (unsigned short)(u >> 16);
}

// ---------------- A (f32) -> bf16 copy ----------------
__global__ void k_conv_a(const float* __restrict__ A, unsigned short* __restrict__ abf, long n){
  long i0 = ((long)blockIdx.x*blockDim.x + threadIdx.x)*4;
  long stride = (long)gridDim.x*blockDim.x*4;
  for (long e = i0; e < n; e += stride){
    float4 v = *(const float4*)(A + e);
    ushort4 o; o.x=f2bf(v.x); o.y=f2bf(v.y); o.z=f2bf(v.z); o.w=f2bf(v.w);
    *(ushort4*)(abf + e) = o;
  }
}

// ---------------- scan-state init ----------------
__global__ void k_init(const float* __restrict__ y0, const float* __restrict__ u0,
                       const float* __restrict__ d0, float* __restrict__ y,
                       float* __restrict__ u, float* __restrict__ dl,
                       unsigned short* __restrict__ ybf, int n){
  int e = (blockIdx.x*blockDim.x + threadIdx.x)*4;
  if (e >= n) return;
  float4 a = *(const float4*)(y0+e);
  *(float4*)(y+e) = a;
  ushort4 o; o.x=f2bf(a.x); o.y=f2bf(a.y); o.z=f2bf(a.z); o.w=f2bf(a.w);
  *(ushort4*)(ybf+e) = o;
  *(float4*)(u+e)  = *(const float4*)(u0+e);
  *(float4*)(dl+e) = *(const float4*)(d0+e);
}

// ---------------- encoder GEMM: out[b,o] = sum_i act(X[b,i]) * W[i,o] ----------------
// partial sums over i-chunks, deterministic reduce afterwards.
__global__ __launch_bounds__(256) void k_enc_gemm(const float* __restrict__ X, const float* __restrict__ W,
                           float* __restrict__ part, int fi, int fo, int ichunk, int actin){
  __shared__ float xs[32][16];   // [i][b], broadcast reads
  const int tid = threadIdx.x;
  const int o1 = blockIdx.x*512 + tid;
  const int o2 = o1 + 256;
  const int c  = blockIdx.y;
  const bool ok1 = o1 < fo, ok2 = o2 < fo;
  float acc[2][16];
  #pragma unroll
  for (int h=0;h<2;h++)
    #pragma unroll
    for (int j=0;j<16;j++) acc[h][j]=0.f;
  for (int t0 = 0; t0 < ichunk; t0 += 32){
    const int i0 = c*ichunk + t0;
    { // stage X transposed: 32 i x 16 b
      int e = tid*2;
      int i = e >> 4, b0 = e & 15;
      float v0 = X[(long)b0*fi + i0 + i];
      float v1 = X[(long)(b0+1)*fi + i0 + i];
      if (actin){ v0 = lrelu(v0); v1 = lrelu(v1); }
      xs[i][b0] = v0; xs[i][b0+1] = v1;
    }
    __syncthreads();
    for (int ii=0; ii<32; ii++){
      const float4* xr = (const float4*)&xs[ii][0];
      float xv[16];
      *(float4*)&xv[0]=xr[0]; *(float4*)&xv[4]=xr[1]; *(float4*)&xv[8]=xr[2]; *(float4*)&xv[12]=xr[3];
      float w0 = ok1 ? W[(long)(i0+ii)*fo + o1] : 0.f;
      float w1 = ok2 ? W[(long)(i0+ii)*fo + o2] : 0.f;
      #pragma unroll
      for (int j=0;j<16;j++){ acc[0][j] += w0*xv[j]; acc[1][j] += w1*xv[j]; }
    }
    __syncthreads();
  }
  float* pp = part + (long)c*16*fo;
  if (ok1){
    #pragma unroll
    for (int j=0;j<16;j++) pp[(long)j*fo + o1] = acc[0][j];
  }
  if (ok2){
    #pragma unroll
    for (int j=0;j<16;j++) pp[(long)j*fo + o2] = acc[1][j];
  }
}

__global__ void k_enc_reduce(const float* __restrict__ part, const float* __restrict__ bias,
                             float* __restrict__ out, int fo, int nchunk){
  int i = blockIdx.x*256 + threadIdx.x;
  if (i >= 16*fo) return;
  int o = i % fo;
  float s = bias[o];
  for (int c=0;c<nchunk;c++) s += part[(long)c*16*fo + i];
  out[i] = s;
}

// ---------------- per-batch graph matrices ----------------
// Adj: normalized adjacency (incl. self term), Dm: delta operator, snb: src counts.
// LDS atomic adds are of EQUAL values per cell -> order-independent -> deterministic.
__global__ __launch_bounds__(64) void k_graph(const int* __restrict__ ei, float* __restrict__ adjg,
                        float* __restrict__ dmg, float* __restrict__ snbg){
  const int b = blockIdx.x, tid = threadIdx.x;
  __shared__ float adj[2500], dm[2500], deg[50], dinv[50], snb[50];
  for (int i=tid;i<2500;i+=64){ adj[i]=0.f; dm[i]=0.f; }
  if (tid<50){ deg[tid]=0.f; snb[tid]=0.f; }
  __syncthreads();
  const int* e = ei + b*800;   // [0..399]=src, [400..799]=dst
  for (int k=tid;k<400;k+=64){
    atomicAdd(&deg[e[400+k]], 1.f);
    atomicAdd(&snb[e[k]], 1.f);
  }
  __syncthreads();
  if (tid<50) dinv[tid] = 1.f / sqrtf(deg[tid] + 1.f);
  __syncthreads();
  for (int k=tid;k<400;k+=64){
    int s = e[k], d = e[400+k];
    atomicAdd(&adj[d*50+s], dinv[s]*dinv[d]);
    atomicAdd(&dm[s*50+s],  1.f); atomicAdd(&dm[s*50+d], -1.f);
    atomicAdd(&dm[d*50+d],  1.f); atomicAdd(&dm[d*50+s], -1.f);
  }
  __syncthreads();
  if (tid<50) adj[tid*50+tid] += dinv[tid]*dinv[tid];
  __syncthreads();
  for (int i=tid;i<2500;i+=64){ adjg[b*2500+i]=adj[i]; dmg[b*2500+i]=dm[i]; }
  if (tid<50) snbg[b*50+tid]=snb[tid];
}

// ---------------- GCN layer: xout = lrelu(Adj @ (xin @ W) + bias) ----------------
__global__ __launch_bounds__(256) void k_gcn(const float* __restrict__ xin, int fin,
                      const float* __restrict__ W, const float* __restrict__ bias,
                      const float* __restrict__ adjg, float* __restrict__ xout){
  const int b = blockIdx.x, jh = blockIdx.y, tid = threadIdx.x;
  __shared__ float h[50][64];
  const float* xb = xin + (long)b*50*fin;
  for (int idx=tid; idx<3200; idx+=256){
    int n = idx>>6, j = idx&63;
    float s = 0.f;
    for (int i=0;i<fin;i++) s += xb[n*fin+i]*W[i*128 + jh*64 + j];
    h[n][j] = s;
  }
  __syncthreads();
  const float* adj = adjg + b*2500;
  for (int idx=tid; idx<3200; idx+=256){
    int n = idx>>6, j = idx&63;
    float s = bias[jh*64+j];
    for (int q=0;q<50;q++) s += adj[n*50+q]*h[q][j];
    xout[((long)b*50+n)*128 + jh*64 + j] = lrelu(s);
  }
}

// ---------------- head: mean -> fc1 -> fc2 -> cumsum -> sigmoid * max_param ----------------
__global__ __launch_bounds__(128) void k_head(const float* __restrict__ x2, const float* __restrict__ Wf1,
                       const float* __restrict__ bf1, const float* __restrict__ Wf2,
                       const float* __restrict__ bf2, const float* __restrict__ maxp,
                       float* __restrict__ hypg){
  const int b = blockIdx.x, tid = threadIdx.x;
  __shared__ float xm[128], hh[64], raw[80];
  const float* xb = x2 + (long)b*50*128;
  {
    float s = 0.f;
    for (int n=0;n<50;n++) s += xb[n*128 + tid];
    xm[tid] = s * (1.f/50.f);
  }
  __syncthreads();
  if (tid < 64){
    float s = bf1[tid];
    for (int i=0;i<128;i++) s += xm[i]*Wf1[i*64 + tid];
    hh[tid] = lrelu(s);
  }
  __syncthreads();
  if (tid < 80){
    float s = bf2[tid];
    for (int i=0;i<64;i++) s += hh[i]*Wf2[i*80 + tid];
    raw[tid] = s;
  }
  __syncthreads();
  if (tid < 4){
    float c = 0.f;
    for (int k=0;k<20;k++){
      c += raw[k*4 + tid];
      hypg[b*80 + k*4 + tid] = maxp[tid] / (1.f + expf(-c));
    }
  }
}

// ---------------- t[b,p,m] = sum_n Abf[p,m,n] * ybf[b,p,n] ----------------
__global__ __launch_bounds__(128) void k_g1(const unsigned short* __restrict__ abf,
                     const unsigned short* __restrict__ ybf, float* __restrict__ t){
  const int p = blockIdx.x;
  const int m0 = blockIdx.y * 64;
  const int tid = threadIdx.x;
  const int tm = tid >> 2;   // 0..31
  const int tb = tid & 3;    // 0..3
  __shared__ float al[64][132];
  __shared__ float yl[16][132];
  float acc[2][4];
  #pragma unroll
  for (int h=0;h<2;h++)
    #pragma unroll
    for (int j=0;j<4;j++) acc[h][j]=0.f;
  for (int nt=0; nt<8; nt++){
    const int ns = nt*128;
    #pragma unroll
    for (int rep=0; rep<8; rep++){     // stage A: 64 x 128 bf16 -> f32
      int e = (rep*128 + tid)*8;
      int r = e >> 7, cc = e & 127;
      uint4 rw = *(const uint4*)(abf + ((long)p*NM + m0 + r)*NN + ns + cc);
      const unsigned short* us = (const unsigned short*)&rw;
      #pragma unroll
      for (int q=0;q<8;q++) al[r][cc+q] = bfu(us[q]);
    }
    #pragma unroll
    for (int rep=0; rep<2; rep++){     // stage y: 16 x 128
      int e = (rep*128 + tid)*8;
      int r = e >> 7, cc = e & 127;
      uint4 rw = *(const uint4*)(ybf + ((long)r*NP + p)*NN + ns + cc);
      const unsigned short* us = (const unsigned short*)&rw;
      #pragma unroll
      for (int q=0;q<8;q++) yl[r][cc+q] = bfu(us[q]);
    }
    __syncthreads();
    for (int nn=0; nn<128; nn+=4){
      float4 a0 = *(const float4*)&al[tm][nn];
      float4 a1 = *(const float4*)&al[tm+32][nn];
      #pragma unroll
      for (int j=0;j<4;j++){
        float4 yv = *(const float4*)&yl[tb*4+j][nn];
        acc[0][j] += a0.x*yv.x; acc[0][j] += a0.y*yv.y;
        acc[0][j] += a0.z*yv.z; acc[0][j] += a0.w*yv.w;
        acc[1][j] += a1.x*yv.x; acc[1][j] += a1.y*yv.y;
        acc[1][j] += a1.z*yv.z; acc[1][j] += a1.w*yv.w;
      }
    }
    __syncthreads();
  }
  #pragma unroll
  for (int h=0;h<2;h++){
    int m = m0 + tm + 32*h;
    #pragma unroll
    for (int j=0;j<4;j++) t[((long)(tb*4+j)*NP + p)*NM + m] = acc[h][j];
  }
}

// ---------------- z[b,p,n] = sum_m Abf[p,m,n] * src[b,p,m]  (also computes Atb) ----------------
__global__ __launch_bounds__(256) void k_gat(const unsigned short* __restrict__ abf,
                      const float* __restrict__ src, float* __restrict__ z){
  const int p = blockIdx.x;
  const int n0 = blockIdx.y * 128;
  const int tid = threadIdx.x;
  const int tn = tid & 127;
  const int tbh = tid >> 7;
  __shared__ float tl[16][512];
  #pragma unroll
  for (int rep=0; rep<8; rep++){
    int e = (rep*256 + tid)*4;
    int r = e >> 9, m = e & 511;
    *(float4*)&tl[r][m] = *(const float4*)(src + ((long)r*NP + p)*NM + m);
  }
  __syncthreads();
  float acc[8];
  #pragma unroll
  for (int j=0;j<8;j++) acc[j]=0.f;
  const unsigned short* ab = abf + (long)p*NM*NN + n0 + tn;
  for (int mc=0; mc<64; mc++){
    float tr[8][8];
    #pragma unroll
    for (int j=0;j<8;j++){
      float4 u0v = *(const float4*)&tl[tbh*8+j][mc*8];
      float4 u1v = *(const float4*)&tl[tbh*8+j][mc*8+4];
      tr[j][0]=u0v.x; tr[j][1]=u0v.y; tr[j][2]=u0v.z; tr[j][3]=u0v.w;
      tr[j][4]=u1v.x; tr[j][5]=u1v.y; tr[j][6]=u1v.z; tr[j][7]=u1v.w;
    }
    #pragma unroll
    for (int mm=0; mm<8; mm++){
      float a = bfu(ab[(long)(mc*8+mm)*NN]);
      #pragma unroll
      for (int j=0;j<8;j++) acc[j] += a * tr[j][mm];
    }
  }
  #pragma unroll
  for (int j=0;j<8;j++)
    z[((long)(tbh*8+j)*NP + p)*NN + n0 + tn] = acc[j];
}

// ---------------- fused scan update ----------------
__global__ __launch_bounds__(256) void k_upd(const float* __restrict__ zz, const float* __restrict__ atb,
                      const float* __restrict__ dmg, const float* __restrict__ snbg,
                      const float* __restrict__ hypg, int k,
                      float* __restrict__ y, unsigned short* __restrict__ ybf,
                      float* __restrict__ u, float* __restrict__ dl,
                      float* __restrict__ yout){
  const int b = blockIdx.x;
  const int n = blockIdx.y*256 + threadIdx.x;
  __shared__ float yn[50][257];
  const float alpha = hypg[b*80 + k*4 + 0];
  const float tau   = hypg[b*80 + k*4 + 1];
  const float rho   = hypg[b*80 + k*4 + 2];
  const float eta   = hypg[b*80 + k*4 + 3];
  const long base = (long)b*NP*NN + n;
  for (int p=0;p<NP;p++){
    const long idx = base + (long)p*NN;
    float yv = y[idx];
    float g = zz[idx] - atb[idx]
            + ((yv>0.f)?1.f:((yv<0.f)?-1.f:0.f))*tau
            + u[idx]*snbg[b*NP+p] + dl[idx]*rho;
    float ynv = yv - alpha*g;
    yn[p][threadIdx.x] = ynv;
    y[idx] = ynv;
    ybf[idx] = f2bf(ynv);
    yout[(long)k*YSZ + idx] = ynv;
  }
  __syncthreads();
  const float* dmb = dmg + b*2500;
  for (int p=0;p<NP;p++){
    float s = 0.f;
    #pragma unroll 10
    for (int q=0;q<NP;q++) s += dmb[p*50+q]*yn[q][threadIdx.x];
    const long idx = base + (long)p*NN;
    dl[idx] = s;
    u[idx] += s*eta;
  }
}

extern "C" void kernel_launch(void* const* d_in, const int* in_sizes, int n_in,
                              void* d_out, int out_size, void* d_ws, size_t ws_size,
                              hipStream_t stream){
  (void)in_sizes; (void)n_in; (void)out_size; (void)ws_size;
  const float* bin = (const float*)d_in[0];
  const float* A   = (const float*)d_in[1];
  const int*   ei  = (const int*)d_in[2];
  const float* mxp = (const float*)d_in[3];
  const float* We1 = (const float*)d_in[4];  const float* be1 = (const float*)d_in[5];
  const float* We2 = (const float*)d_in[6];  const float* be2 = (const float*)d_in[7];
  const float* We3 = (const float*)d_in[8];  const float* be3 = (const float*)d_in[9];
  const float* Wc1 = (const float*)d_in[10]; const float* bc1 = (const float*)d_in[11];
  const float* Wc2 = (const float*)d_in[12]; const float* bc2 = (const float*)d_in[13];
  const float* Wf1 = (const float*)d_in[14]; const float* bf1 = (const float*)d_in[15];
  const float* Wf2 = (const float*)d_in[16]; const float* bf2 = (const float*)d_in[17];
  const float* y0  = (const float*)d_in[18];
  const float* u0  = (const float*)d_in[19];
  const float* dd0 = (const float*)d_in[20];
  float* out = (float*)d_out;

  char* cur = (char*)d_ws;
  auto alloc = [&](size_t bytes)->void*{
    void* pp = (void*)cur; cur += (bytes + 255) & ~(size_t)255; return pp;
  };
  unsigned short* abf = (unsigned short*)alloc(ASZ*2);     // 52.4 MB, L3-resident
  float* atb = (float*)alloc(YSZ*4);
  float* y   = (float*)alloc(YSZ*4);
  unsigned short* ybf = (unsigned short*)alloc(YSZ*2);
  float* u   = (float*)alloc(YSZ*4);
  float* dl  = (float*)alloc(YSZ*4);
  float* t   = (float*)alloc((size_t)NB*NP*NM*4);
  float* z   = (float*)alloc(YSZ*4);
  float* h1  = (float*)alloc((size_t)16*3200*4);
  float* h2  = (float*)alloc((size_t)16*6400*4);
  float* h3  = (float*)alloc((size_t)16*12800*4);
  float* x1  = (float*)alloc((size_t)16*50*128*4);
  float* x2  = (float*)alloc((size_t)16*50*128*4);
  float* adj = (float*)alloc((size_t)16*2500*4);
  float* dm  = (float*)alloc((size_t)16*2500*4);
  float* snb = (float*)alloc((size_t)16*50*4);
  float* hyp = (float*)alloc((size_t)16*80*4);
  float* part= (float*)alloc((size_t)8192000);             // shared partial buffer

  // ---- one-time prep ----
  k_conv_a<<<dim3(4096), dim3(256), 0, stream>>>(A, abf, ASZ);
  k_init<<<dim3(800), dim3(256), 0, stream>>>(y0, u0, dd0, y, u, dl, ybf, (int)YSZ);
  k_gat<<<dim3(50,8), dim3(256), 0, stream>>>(abf, bin, atb);          // Atb = A^T b

  // ---- encoder MLP (HBM-bound on weights) ----
  k_enc_gemm<<<dim3(7,40),  dim3(256), 0, stream>>>(bin, We1, part, 25600, 3200, 640, 0);
  k_enc_reduce<<<dim3(200), dim3(256), 0, stream>>>(part, be1, h1, 3200, 40);
  k_enc_gemm<<<dim3(13,20), dim3(256), 0, stream>>>(h1, We2, part, 3200, 6400, 160, 1);
  k_enc_reduce<<<dim3(400), dim3(256), 0, stream>>>(part, be2, h2, 6400, 20);
  k_enc_gemm<<<dim3(25,10), dim3(256), 0, stream>>>(h2, We3, part, 6400, 12800, 640, 1);
  k_enc_reduce<<<dim3(800), dim3(256), 0, stream>>>(part, be3, h3, 12800, 10);

  // ---- graph + GCN + hyper head ----
  k_graph<<<dim3(16), dim3(64), 0, stream>>>(ei, adj, dm, snb);
  k_gcn<<<dim3(16,2), dim3(256), 0, stream>>>(h3, 256, Wc1, bc1, adj, x1);
  k_gcn<<<dim3(16,2), dim3(256), 0, stream>>>(x1, 128, Wc2, bc2, adj, x2);
  k_head<<<dim3(16), dim3(128), 0, stream>>>(x2, Wf1, bf1, Wf2, bf2, mxp, hyp);

  // ---- scan: y_{k+1} = y_k - alpha*(A^T(A y_k) - Atb + sign*tau + U*snb + dlt*rho); dlt=Dm@y; U+=dlt*eta
  for (int k=0;k<NK;k++){
    k_g1 <<<dim3(50,8), dim3(128), 0, stream>>>(abf, ybf, t);
    k_gat<<<dim3(50,8), dim3(256), 0, stream>>>(abf, t, z);
    k_upd<<<dim3(16,4), dim3(256), 0, stream>>>(z, atb, dm, snb, hyp, k, y, ybf, u, dl, out);
  }
}

// Round 3
// 1878.797 us; speedup vs baseline: 2.3160x; 2.3160x over previous
//
#include <hip/hip_runtime.h>

namespace {
constexpr int NB = 16;    // batch
constexpr int NP = 50;    // P nodes
constexpr int NM = 512;   // M
constexpr int NN = 1024;  // N
constexpr int NK = 20;    // scan steps
constexpr long ASZ = (long)NP * NM * NN;   // 26,214,400
constexpr long YSZ = (long)NB * NP * NN;   // 819,200
}

typedef __attribute__((ext_vector_type(8))) short bf16x8;
typedef __attribute__((ext_vector_type(4))) float f32x4;

__device__ __forceinline__ float lrelu(float x){ return x > 0.f ? x : 0.01f*x; }
__device__ __forceinline__ float bfu(unsigned short x){
  unsigned v = ((unsigned)x) << 16;
  return __builtin_bit_cast(float, v);
}
__device__ __forceinline__ unsigned short f2bf(float f){   // RNE f32->bf16
  unsigned u = __builtin_bit_cast(unsigned, f);
  u += 0x7fffu + ((u >> 16) & 1u);
  return (unsigned short)(u >> 16);
}

// ---------------- one-pass A (f32) -> abf (row-major bf16) + abfT (transposed bf16) ----------------
__global__ __launch_bounds__(256) void k_prep(const float* __restrict__ A,
                      unsigned short* __restrict__ abf, unsigned short* __restrict__ abfT){
  const int p = blockIdx.x, mt = blockIdx.y, nt = blockIdx.z;
  const int tid = threadIdx.x;
  __shared__ unsigned short tile[64][72];
  const int m0 = mt*64, n0 = nt*64;
  {
    int r = tid>>2, cs = (tid&3)*16;
    const float* src = A + ((long)p*NM + m0 + r)*NN + n0 + cs;
    unsigned short tmp[16];
    #pragma unroll
    for (int q=0;q<16;q+=4){
      float4 v = *(const float4*)(src+q);
      tmp[q+0]=f2bf(v.x); tmp[q+1]=f2bf(v.y); tmp[q+2]=f2bf(v.z); tmp[q+3]=f2bf(v.w);
    }
    #pragma unroll
    for (int q=0;q<16;q++) tile[r][cs+q] = tmp[q];
    unsigned short* dst = abf + ((long)p*NM + m0 + r)*NN + n0 + cs;
    #pragma unroll
    for (int q=0;q<16;q+=8) *(uint4*)(dst+q) = *(const uint4*)&tmp[q];
  }
  __syncthreads();
  {
    int r = tid>>2, cs = (tid&3)*16;   // r = n-offset, cs = m-offset
    unsigned short* dst = abfT + ((long)p*NN + n0 + r)*NM + m0 + cs;
    unsigned short tmp[16];
    #pragma unroll
    for (int q=0;q<16;q++) tmp[q] = tile[cs+q][r];
    #pragma unroll
    for (int q=0;q<16;q+=8) *(uint4*)(dst+q) = *(const uint4*)&tmp[q];
  }
}

// ---------------- scan-state init ----------------
__global__ void k_init(const float* __restrict__ y0, const float* __restrict__ u0,
                       const float* __restrict__ d0, float* __restrict__ y,
                       float* __restrict__ u, float* __restrict__ dl,
                       unsigned short* __restrict__ ybf, int n){
  int e = (blockIdx.x*blockDim.x + threadIdx.x)*4;
  if (e >= n) return;
  float4 a = *(const float4*)(y0+e);
  *(float4*)(y+e) = a;
  ushort4 o; o.x=f2bf(a.x); o.y=f2bf(a.y); o.z=f2bf(a.z); o.w=f2bf(a.w);
  *(ushort4*)(ybf+e) = o;
  *(float4*)(u+e)  = *(const float4*)(u0+e);
  *(float4*)(dl+e) = *(const float4*)(d0+e);
}

// ---------------- encoder GEMM (unchanged: HBM-bound weight stream) ----------------
__global__ __launch_bounds__(256) void k_enc_gemm(const float* __restrict__ X, const float* __restrict__ W,
                           float* __restrict__ part, int fi, int fo, int ichunk, int actin){
  __shared__ float xs[32][16];
  const int tid = threadIdx.x;
  const int o1 = blockIdx.x*512 + tid;
  const int o2 = o1 + 256;
  const int c  = blockIdx.y;
  const bool ok1 = o1 < fo, ok2 = o2 < fo;
  float acc[2][16];
  #pragma unroll
  for (int h=0;h<2;h++)
    #pragma unroll
    for (int j=0;j<16;j++) acc[h][j]=0.f;
  for (int t0 = 0; t0 < ichunk; t0 += 32){
    const int i0 = c*ichunk + t0;
    {
      int e = tid*2;
      int i = e >> 4, b0 = e & 15;
      float v0 = X[(long)b0*fi + i0 + i];
      float v1 = X[(long)(b0+1)*fi + i0 + i];
      if (actin){ v0 = lrelu(v0); v1 = lrelu(v1); }
      xs[i][b0] = v0; xs[i][b0+1] = v1;
    }
    __syncthreads();
    for (int ii=0; ii<32; ii++){
      const float4* xr = (const float4*)&xs[ii][0];
      float xv[16];
      *(float4*)&xv[0]=xr[0]; *(float4*)&xv[4]=xr[1]; *(float4*)&xv[8]=xr[2]; *(float4*)&xv[12]=xr[3];
      float w0 = ok1 ? W[(long)(i0+ii)*fo + o1] : 0.f;
      float w1 = ok2 ? W[(long)(i0+ii)*fo + o2] : 0.f;
      #pragma unroll
      for (int j=0;j<16;j++){ acc[0][j] += w0*xv[j]; acc[1][j] += w1*xv[j]; }
    }
    __syncthreads();
  }
  float* pp = part + (long)c*16*fo;
  if (ok1){
    #pragma unroll
    for (int j=0;j<16;j++) pp[(long)j*fo + o1] = acc[0][j];
  }
  if (ok2){
    #pragma unroll
    for (int j=0;j<16;j++) pp[(long)j*fo + o2] = acc[1][j];
  }
}

__global__ void k_enc_reduce(const float* __restrict__ part, const float* __restrict__ bias,
                             float* __restrict__ out, int fo, int nchunk){
  int i = blockIdx.x*256 + threadIdx.x;
  if (i >= 16*fo) return;
  int o = i % fo;
  float s = bias[o];
  for (int c=0;c<nchunk;c++) s += part[(long)c*16*fo + i];
  out[i] = s;
}

// ---------------- per-batch graph matrices ----------------
__global__ __launch_bounds__(64) void k_graph(const int* __restrict__ ei, float* __restrict__ adjg,
                        float* __restrict__ dmg, float* __restrict__ snbg){
  const int b = blockIdx.x, tid = threadIdx.x;
  __shared__ float adj[2500], dm[2500], deg[50], dinv[50], snb[50];
  for (int i=tid;i<2500;i+=64){ adj[i]=0.f; dm[i]=0.f; }
  if (tid<50){ deg[tid]=0.f; snb[tid]=0.f; }
  __syncthreads();
  const int* e = ei + b*800;
  for (int k=tid;k<400;k+=64){
    atomicAdd(&deg[e[400+k]], 1.f);
    atomicAdd(&snb[e[k]], 1.f);
  }
  __syncthreads();
  if (tid<50) dinv[tid] = 1.f / sqrtf(deg[tid] + 1.f);
  __syncthreads();
  for (int k=tid;k<400;k+=64){
    int s = e[k], d = e[400+k];
    atomicAdd(&adj[d*50+s], dinv[s]*dinv[d]);
    atomicAdd(&dm[s*50+s],  1.f); atomicAdd(&dm[s*50+d], -1.f);
    atomicAdd(&dm[d*50+d],  1.f); atomicAdd(&dm[d*50+s], -1.f);
  }
  __syncthreads();
  if (tid<50) adj[tid*50+tid] += dinv[tid]*dinv[tid];
  __syncthreads();
  for (int i=tid;i<2500;i+=64){ adjg[b*2500+i]=adj[i]; dmg[b*2500+i]=dm[i]; }
  if (tid<50) snbg[b*50+tid]=snb[tid];
}

// ---------------- fused GCN x2 + head, one block per batch, all-LDS ----------------
__global__ __launch_bounds__(256) void k_gnn(const float* __restrict__ h3,
     const float* __restrict__ Wc1, const float* __restrict__ bc1,
     const float* __restrict__ Wc2, const float* __restrict__ bc2,
     const float* __restrict__ Wf1, const float* __restrict__ bf1,
     const float* __restrict__ Wf2, const float* __restrict__ bf2,
     const float* __restrict__ maxp, const float* __restrict__ adjg,
     float* __restrict__ hypg){
  const int b = blockIdx.x, tid = threadIdx.x;
  __shared__ float adj[2500];
  __shared__ float bufA[6400];   // hh / h2
  __shared__ float bufB[6400];   // xchunk / x1 / x2
  __shared__ float xm[128], hv1[64], raw[80];
  for (int i=tid;i<2500;i+=256) adj[i] = adjg[b*2500+i];

  const int j = tid & 127, nh = tid >> 7;
  float acc[25];
  #pragma unroll
  for (int q=0;q<25;q++) acc[q]=0.f;
  // layer1 phase1: hh[n][j] = sum_{i<256} x[n][i]*Wc1[i*128+j], x staged in 4 chunks of 64
  for (int ic=0; ic<4; ic++){
    __syncthreads();
    for (int e=tid; e<800; e+=256){
      int n = e>>4, seg = (e&15)*4;
      *(float4*)&bufB[n*64+seg] = *(const float4*)(h3 + (long)b*12800 + n*256 + ic*64 + seg);
    }
    __syncthreads();
    for (int i=0;i<64;i+=4){
      float w0 = Wc1[(long)(ic*64+i+0)*128 + j];
      float w1 = Wc1[(long)(ic*64+i+1)*128 + j];
      float w2 = Wc1[(long)(ic*64+i+2)*128 + j];
      float w3 = Wc1[(long)(ic*64+i+3)*128 + j];
      #pragma unroll
      for (int q=0;q<25;q++){
        float4 xv = *(const float4*)&bufB[(nh*25+q)*64 + i];
        acc[q] += xv.x*w0 + xv.y*w1 + xv.z*w2 + xv.w*w3;
      }
    }
  }
  __syncthreads();
  #pragma unroll
  for (int q=0;q<25;q++) bufA[(nh*25+q)*128 + j] = acc[q];
  __syncthreads();
  // layer1 phase2: x1[n][j] = lrelu(bc1 + adj@hh)
  {
    float a2[25];
    float bv = bc1[j];
    #pragma unroll
    for (int q=0;q<25;q++) a2[q]=bv;
    for (int qq=0; qq<50; qq++){
      float hvv = bufA[qq*128 + j];
      #pragma unroll
      for (int q=0;q<25;q++) a2[q] += adj[(nh*25+q)*50 + qq]*hvv;
    }
    __syncthreads();
    #pragma unroll
    for (int q=0;q<25;q++) bufB[(nh*25+q)*128 + j] = lrelu(a2[q]);
  }
  __syncthreads();
  // layer2 phase1: h2[n][j] = sum_{i<128} x1[n][i]*Wc2[i*128+j]
  {
    float a2[25];
    #pragma unroll
    for (int q=0;q<25;q++) a2[q]=0.f;
    for (int i=0;i<128;i+=4){
      float w0 = Wc2[(long)(i+0)*128 + j];
      float w1 = Wc2[(long)(i+1)*128 + j];
      float w2 = Wc2[(long)(i+2)*128 + j];
      float w3 = Wc2[(long)(i+3)*128 + j];
      #pragma unroll
      for (int q=0;q<25;q++){
        float4 xv = *(const float4*)&bufB[(nh*25+q)*128 + i];
        a2[q] += xv.x*w0 + xv.y*w1 + xv.z*w2 + xv.w*w3;
      }
    }
    __syncthreads();
    #pragma unroll
    for (int q=0;q<25;q++) bufA[(nh*25+q)*128 + j] = a2[q];
  }
  __syncthreads();
  // layer2 phase2: x2 = lrelu(bc2 + adj@h2) -> bufB
  {
    float a2[25];
    float bv = bc2[j];
    #pragma unroll
    for (int q=0;q<25;q++) a2[q]=bv;
    for (int qq=0; qq<50; qq++){
      float hvv = bufA[qq*128 + j];
      #pragma unroll
      for (int q=0;q<25;q++) a2[q] += adj[(nh*25+q)*50 + qq]*hvv;
    }
    __syncthreads();
    #pragma unroll
    for (int q=0;q<25;q++) bufB[(nh*25+q)*128 + j] = lrelu(a2[q]);
  }
  __syncthreads();
  // head
  if (tid < 128){
    float s = 0.f;
    for (int n=0;n<50;n++) s += bufB[n*128 + tid];
    xm[tid] = s * (1.f/50.f);
  }
  __syncthreads();
  if (tid < 64){
    float s = bf1[tid];
    for (int i=0;i<128;i++) s += xm[i]*Wf1[i*64 + tid];
    hv1[tid] = lrelu(s);
  }
  __syncthreads();
  if (tid < 80){
    float s = bf2[tid];
    for (int i=0;i<64;i++) s += hv1[i]*Wf2[i*80 + tid];
    raw[tid] = s;
  }
  __syncthreads();
  if (tid < 4){
    float c = 0.f;
    for (int k=0;k<20;k++){
      c += raw[k*4 + tid];
      hypg[b*80 + k*4 + tid] = maxp[tid] / (1.f + expf(-c));
    }
  }
}

// ---------------- MFMA: t[b,p,m] = sum_n A[p,m,n]*y[b,p,n]  (M=512,N=16,K=1024) ----------------
__global__ __launch_bounds__(256) void k_g1m(const unsigned short* __restrict__ abf,
                      const unsigned short* __restrict__ ybf, unsigned short* __restrict__ tbf){
  const int p = blockIdx.x;
  const int wave = threadIdx.x>>6, lane = threadIdx.x&63;
  const int mt = blockIdx.y*4 + wave, m0 = mt*16;
  const int lr = lane&15, kg = lane>>4;
  const unsigned short* ap = abf + ((long)p*NM + m0 + lr)*NN + kg*8;   // A row m0+lr
  const unsigned short* yp = ybf + ((long)lr*NP + p)*NN + kg*8;        // B col b=lr
  f32x4 acc = {0.f,0.f,0.f,0.f};
  #pragma unroll 8
  for (int ks=0; ks<32; ks++){
    bf16x8 av = *(const bf16x8*)(ap + ks*32);
    bf16x8 bv = *(const bf16x8*)(yp + ks*32);
    acc = __builtin_amdgcn_mfma_f32_16x16x32_bf16(av, bv, acc, 0, 0, 0);
  }
  #pragma unroll
  for (int r=0;r<4;r++){
    int m = m0 + kg*4 + r;                    // D row
    tbf[((long)lr*NP + p)*NM + m] = f2bf(acc[r]);   // D col = b = lr
  }
}

// ---------------- MFMA: z[b,p,n] = sum_m A[p,m,n]*src[b,p,m]  (via abfT; M=16,N=1024,K=512) ----------------
template<bool BF16IN>
__global__ __launch_bounds__(256) void k_gatm(const unsigned short* __restrict__ abfT,
                      const void* __restrict__ srcv, float* __restrict__ z){
  const int p = blockIdx.x;
  const int wave = threadIdx.x>>6, lane = threadIdx.x&63;
  const int nt = blockIdx.y*4 + wave, n0 = nt*16;
  const int lr = lane&15, kg = lane>>4;
  const unsigned short* bp = abfT + ((long)p*NN + n0 + lr)*NM + kg*8;  // B col n0+lr, k=m
  f32x4 acc = {0.f,0.f,0.f,0.f};
  #pragma unroll 4
  for (int ks=0; ks<16; ks++){
    bf16x8 av;
    if constexpr (BF16IN){
      av = *(const bf16x8*)((const unsigned short*)srcv + ((long)lr*NP + p)*NM + ks*32 + kg*8);
    } else {
      const float* tp = (const float*)srcv + ((long)lr*NP + p)*NM + ks*32 + kg*8;
      float4 lo = *(const float4*)tp, hi = *(const float4*)(tp+4);
      union { bf16x8 v; unsigned short u[8]; } cv;
      cv.u[0]=f2bf(lo.x); cv.u[1]=f2bf(lo.y); cv.u[2]=f2bf(lo.z); cv.u[3]=f2bf(lo.w);
      cv.u[4]=f2bf(hi.x); cv.u[5]=f2bf(hi.y); cv.u[6]=f2bf(hi.z); cv.u[7]=f2bf(hi.w);
      av = cv.v;
    }
    bf16x8 bv = *(const bf16x8*)(bp + ks*32);
    acc = __builtin_amdgcn_mfma_f32_16x16x32_bf16(av, bv, acc, 0, 0, 0);
  }
  #pragma unroll
  for (int r=0;r<4;r++){
    int bb = kg*4 + r;                                  // D row = b
    z[((long)bb*NP + p)*NN + n0 + lr] = acc[r];         // D col = n
  }
}

// ---------------- fused scan update ----------------
__global__ __launch_bounds__(256) void k_upd(const float* __restrict__ zz, const float* __restrict__ atb,
                      const float* __restrict__ dmg, const float* __restrict__ snbg,
                      const float* __restrict__ hypg, int k,
                      float* __restrict__ y, unsigned short* __restrict__ ybf,
                      float* __restrict__ u, float* __restrict__ dl,
                      float* __restrict__ yout){
  const int b = blockIdx.x;
  const int n0 = blockIdx.y*128;
  const int tid = threadIdx.x;
  __shared__ float yn[50][128];
  __shared__ float dms[2500];
  __shared__ float sa[4];
  if (tid<4) sa[tid] = hypg[b*80 + k*4 + tid];
  for (int i=tid;i<2500;i+=256) dms[i] = dmg[b*2500+i];
  __syncthreads();
  const float alpha = sa[0], tau = sa[1], rho = sa[2], eta = sa[3];
  for (int e=tid; e<6400; e+=256){
    const int p = e>>7, nn = e&127;
    const long idx = ((long)b*NP + p)*NN + n0 + nn;
    float yv = y[idx];
    float g = zz[idx] - atb[idx]
            + ((yv>0.f)?1.f:((yv<0.f)?-1.f:0.f))*tau
            + u[idx]*snbg[b*NP+p] + dl[idx]*rho;
    float ynv = yv - alpha*g;
    yn[p][nn] = ynv;
    y[idx] = ynv;
    ybf[idx] = f2bf(ynv);
    yout[(long)k*YSZ + idx] = ynv;
  }
  __syncthreads();
  for (int e=tid; e<6400; e+=256){
    const int p = e>>7, nn = e&127;
    float s = 0.f;
    #pragma unroll 10
    for (int q=0;q<NP;q++) s += dms[p*50+q]*yn[q][nn];
    const long idx = ((long)b*NP + p)*NN + n0 + nn;
    dl[idx] = s;
    u[idx] += s*eta;
  }
}

extern "C" void kernel_launch(void* const* d_in, const int* in_sizes, int n_in,
                              void* d_out, int out_size, void* d_ws, size_t ws_size,
                              hipStream_t stream){
  (void)in_sizes; (void)n_in; (void)out_size; (void)ws_size;
  const float* bin = (const float*)d_in[0];
  const float* A   = (const float*)d_in[1];
  const int*   ei  = (const int*)d_in[2];
  const float* mxp = (const float*)d_in[3];
  const float* We1 = (const float*)d_in[4];  const float* be1 = (const float*)d_in[5];
  const float* We2 = (const float*)d_in[6];  const float* be2 = (const float*)d_in[7];
  const float* We3 = (const float*)d_in[8];  const float* be3 = (const float*)d_in[9];
  const float* Wc1 = (const float*)d_in[10]; const float* bc1 = (const float*)d_in[11];
  const float* Wc2 = (const float*)d_in[12]; const float* bc2 = (const float*)d_in[13];
  const float* Wf1 = (const float*)d_in[14]; const float* bf1 = (const float*)d_in[15];
  const float* Wf2 = (const float*)d_in[16]; const float* bf2 = (const float*)d_in[17];
  const float* y0  = (const float*)d_in[18];
  const float* u0  = (const float*)d_in[19];
  const float* dd0 = (const float*)d_in[20];
  float* out = (float*)d_out;

  char* cur = (char*)d_ws;
  auto alloc = [&](size_t bytes)->void*{
    void* pp = (void*)cur; cur += (bytes + 255) & ~(size_t)255; return pp;
  };
  unsigned short* abf  = (unsigned short*)alloc(ASZ*2);   // 52.4 MB
  unsigned short* abfT = (unsigned short*)alloc(ASZ*2);   // 52.4 MB
  float* atb = (float*)alloc(YSZ*4);
  float* y   = (float*)alloc(YSZ*4);
  unsigned short* ybf = (unsigned short*)alloc(YSZ*2);
  float* u   = (float*)alloc(YSZ*4);
  float* dl  = (float*)alloc(YSZ*4);
  unsigned short* tbf = (unsigned short*)alloc((size_t)NB*NP*NM*2);
  float* z   = (float*)alloc(YSZ*4);
  float* h1  = (float*)alloc((size_t)16*3200*4);
  float* h2  = (float*)alloc((size_t)16*6400*4);
  float* h3  = (float*)alloc((size_t)16*12800*4);
  float* adj = (float*)alloc((size_t)16*2500*4);
  float* dm  = (float*)alloc((size_t)16*2500*4);
  float* snb = (float*)alloc((size_t)16*50*4);
  float* hyp = (float*)alloc((size_t)16*80*4);
  float* part= (float*)alloc((size_t)8192000);

  // ---- one-time prep ----
  k_prep<<<dim3(50,8,16), dim3(256), 0, stream>>>(A, abf, abfT);
  k_init<<<dim3(800), dim3(256), 0, stream>>>(y0, u0, dd0, y, u, dl, ybf, (int)YSZ);
  k_gatm<false><<<dim3(50,16), dim3(256), 0, stream>>>(abfT, bin, atb);   // Atb = A^T b (f32 in)

  // ---- encoder MLP ----
  k_enc_gemm<<<dim3(7,40),  dim3(256), 0, stream>>>(bin, We1, part, 25600, 3200, 640, 0);
  k_enc_reduce<<<dim3(200), dim3(256), 0, stream>>>(part, be1, h1, 3200, 40);
  k_enc_gemm<<<dim3(13,20), dim3(256), 0, stream>>>(h1, We2, part, 3200, 6400, 160, 1);
  k_enc_reduce<<<dim3(400), dim3(256), 0, stream>>>(part, be2, h2, 6400, 20);
  k_enc_gemm<<<dim3(25,10), dim3(256), 0, stream>>>(h2, We3, part, 6400, 12800, 640, 1);
  k_enc_reduce<<<dim3(800), dim3(256), 0, stream>>>(part, be3, h3, 12800, 10);

  // ---- graph + fused GNN/head ----
  k_graph<<<dim3(16), dim3(64), 0, stream>>>(ei, adj, dm, snb);
  k_gnn<<<dim3(16), dim3(256), 0, stream>>>(h3, Wc1, bc1, Wc2, bc2, Wf1, bf1, Wf2, bf2, mxp, adj, hyp);

  // ---- scan ----
  for (int k=0;k<NK;k++){
    k_g1m<<<dim3(50,8),  dim3(256), 0, stream>>>(abf, ybf, tbf);
    k_gatm<true><<<dim3(50,16), dim3(256), 0, stream>>>(abfT, tbf, z);
    k_upd<<<dim3(16,8),  dim3(256), 0, stream>>>(z, atb, dm, snb, hyp, k, y, ybf, u, dl, out);
  }
}

// Round 4
// 1440.368 us; speedup vs baseline: 3.0210x; 1.3044x over previous
//
#include <hip/hip_runtime.h>

namespace {
constexpr int NB = 16;    // batch
constexpr int NP = 50;    // P nodes
constexpr int NM = 512;   // M
constexpr int NN = 1024;  // N
constexpr int NK = 20;    // scan steps
constexpr long ASZ = (long)NP * NM * NN;   // 26,214,400
constexpr long YSZ = (long)NB * NP * NN;   // 819,200
}

typedef __attribute__((ext_vector_type(8))) short bf16x8;
typedef __attribute__((ext_vector_type(4))) float f32x4;

__device__ __forceinline__ float lrelu(float x){ return x > 0.f ? x : 0.01f*x; }
__device__ __forceinline__ unsigned short f2bf(float f){   // RNE f32->bf16
  unsigned u = __builtin_bit_cast(unsigned, f);
  u += 0x7fffu + ((u >> 16) & 1u);
  return (unsigned short)(u >> 16);
}

// ---------------- one-pass A (f32) -> abf (row-major bf16) + abfT (transposed bf16) ----------------
__global__ __launch_bounds__(256) void k_prep(const float* __restrict__ A,
                      unsigned short* __restrict__ abf, unsigned short* __restrict__ abfT){
  const int p = blockIdx.x, mt = blockIdx.y, nt = blockIdx.z;
  const int tid = threadIdx.x;
  __shared__ unsigned short tile[64][72];
  const int m0 = mt*64, n0 = nt*64;
  {
    int r = tid>>2, cs = (tid&3)*16;
    const float* src = A + ((long)p*NM + m0 + r)*NN + n0 + cs;
    unsigned short tmp[16];
    #pragma unroll
    for (int q=0;q<16;q+=4){
      float4 v = *(const float4*)(src+q);
      tmp[q+0]=f2bf(v.x); tmp[q+1]=f2bf(v.y); tmp[q+2]=f2bf(v.z); tmp[q+3]=f2bf(v.w);
    }
    #pragma unroll
    for (int q=0;q<16;q++) tile[r][cs+q] = tmp[q];
    unsigned short* dst = abf + ((long)p*NM + m0 + r)*NN + n0 + cs;
    #pragma unroll
    for (int q=0;q<16;q+=8) *(uint4*)(dst+q) = *(const uint4*)&tmp[q];
  }
  __syncthreads();
  {
    int r = tid>>2, cs = (tid&3)*16;   // r = n-offset, cs = m-offset
    unsigned short* dst = abfT + ((long)p*NN + n0 + r)*NM + m0 + cs;
    unsigned short tmp[16];
    #pragma unroll
    for (int q=0;q<16;q++) tmp[q] = tile[cs+q][r];
    #pragma unroll
    for (int q=0;q<16;q+=8) *(uint4*)(dst+q) = *(const uint4*)&tmp[q];
  }
}

// ---------------- scan-state init ----------------
__global__ void k_init(const float* __restrict__ y0, const float* __restrict__ u0,
                       const float* __restrict__ d0, float* __restrict__ y,
                       float* __restrict__ u, float* __restrict__ dl,
                       unsigned short* __restrict__ ybf, int n){
  int e = (blockIdx.x*blockDim.x + threadIdx.x)*4;
  if (e >= n) return;
  float4 a = *(const float4*)(y0+e);
  *(float4*)(y+e) = a;
  ushort4 o; o.x=f2bf(a.x); o.y=f2bf(a.y); o.z=f2bf(a.z); o.w=f2bf(a.w);
  *(ushort4*)(ybf+e) = o;
  *(float4*)(u+e)  = *(const float4*)(u0+e);
  *(float4*)(dl+e) = *(const float4*)(d0+e);
}

// ---------------- encoder GEMM v2: float4 W stream, acc[16] float4 ----------------
__global__ __launch_bounds__(256) void k_enc2(const float* __restrict__ X, const float* __restrict__ W,
                           float* __restrict__ part, int fi, int fo, int ichunk, int actin){
  const int tid = threadIdx.x;
  const int o0 = (blockIdx.x*256 + tid)*4;
  const int c  = blockIdx.y;
  const bool ok = o0 < fo;   // fo multiple of 4
  __shared__ float xs[64][16];
  float4 acc[16];
  #pragma unroll
  for (int b=0;b<16;b++){ acc[b].x=0.f; acc[b].y=0.f; acc[b].z=0.f; acc[b].w=0.f; }
  const long ibase = (long)c*ichunk;
  const int xb = tid&15, xio = (tid>>4)*4;
  for (int s=0; s<ichunk; s+=64){
    float4 v = *(const float4*)(X + (long)xb*fi + ibase + s + xio);
    if (actin){ v.x=lrelu(v.x); v.y=lrelu(v.y); v.z=lrelu(v.z); v.w=lrelu(v.w); }
    __syncthreads();
    xs[xio+0][xb]=v.x; xs[xio+1][xb]=v.y; xs[xio+2][xb]=v.z; xs[xio+3][xb]=v.w;
    __syncthreads();
    const float* wp = W + (ibase+s)*fo + o0;
    #pragma unroll 4
    for (int i=0;i<64;i++){
      float4 w;
      if (ok) w = *(const float4*)(wp + (long)i*fo);
      else { w.x=0.f; w.y=0.f; w.z=0.f; w.w=0.f; }
      #pragma unroll
      for (int b2=0;b2<16;b2+=4){
        float4 x4 = *(const float4*)&xs[i][b2];
        acc[b2+0].x += w.x*x4.x; acc[b2+0].y += w.y*x4.x; acc[b2+0].z += w.z*x4.x; acc[b2+0].w += w.w*x4.x;
        acc[b2+1].x += w.x*x4.y; acc[b2+1].y += w.y*x4.y; acc[b2+1].z += w.z*x4.y; acc[b2+1].w += w.w*x4.y;
        acc[b2+2].x += w.x*x4.z; acc[b2+2].y += w.y*x4.z; acc[b2+2].z += w.z*x4.z; acc[b2+2].w += w.w*x4.z;
        acc[b2+3].x += w.x*x4.w; acc[b2+3].y += w.y*x4.w; acc[b2+3].z += w.z*x4.w; acc[b2+3].w += w.w*x4.w;
      }
    }
  }
  if (ok){
    float* pp = part + ((long)c*16)*fo + o0;
    #pragma unroll
    for (int b=0;b<16;b++) *(float4*)(pp + (long)b*fo) = acc[b];
  }
}

__global__ void k_enc_reduce(const float* __restrict__ part, const float* __restrict__ bias,
                             float* __restrict__ out, int fo, int nchunk){
  int i = blockIdx.x*256 + threadIdx.x;
  if (i >= 16*fo) return;
  int o = i % fo;
  float s = bias[o];
  for (int c=0;c<nchunk;c++) s += part[(long)c*16*fo + i];
  out[i] = s;
}

// ---------------- per-batch graph matrices ----------------
__global__ __launch_bounds__(64) void k_graph(const int* __restrict__ ei, float* __restrict__ adjg,
                        float* __restrict__ dmg, float* __restrict__ snbg){
  const int b = blockIdx.x, tid = threadIdx.x;
  __shared__ float adj[2500], dm[2500], deg[50], dinv[50], snb[50];
  for (int i=tid;i<2500;i+=64){ adj[i]=0.f; dm[i]=0.f; }
  if (tid<50){ deg[tid]=0.f; snb[tid]=0.f; }
  __syncthreads();
  const int* e = ei + b*800;
  for (int k=tid;k<400;k+=64){
    atomicAdd(&deg[e[400+k]], 1.f);
    atomicAdd(&snb[e[k]], 1.f);
  }
  __syncthreads();
  if (tid<50) dinv[tid] = 1.f / sqrtf(deg[tid] + 1.f);
  __syncthreads();
  for (int k=tid;k<400;k+=64){
    int s = e[k], d = e[400+k];
    atomicAdd(&adj[d*50+s], dinv[s]*dinv[d]);
    atomicAdd(&dm[s*50+s],  1.f); atomicAdd(&dm[s*50+d], -1.f);
    atomicAdd(&dm[d*50+d],  1.f); atomicAdd(&dm[d*50+s], -1.f);
  }
  __syncthreads();
  if (tid<50) adj[tid*50+tid] += dinv[tid]*dinv[tid];
  __syncthreads();
  for (int i=tid;i<2500;i+=64){ adjg[b*2500+i]=adj[i]; dmg[b*2500+i]=dm[i]; }
  if (tid<50) snbg[b*50+tid]=snb[tid];
}

// ---------------- fused GCN x2 + head ----------------
__global__ __launch_bounds__(256) void k_gnn(const float* __restrict__ h3,
     const float* __restrict__ Wc1, const float* __restrict__ bc1,
     const float* __restrict__ Wc2, const float* __restrict__ bc2,
     const float* __restrict__ Wf1, const float* __restrict__ bf1,
     const float* __restrict__ Wf2, const float* __restrict__ bf2,
     const float* __restrict__ maxp, const float* __restrict__ adjg,
     float* __restrict__ hypg){
  const int b = blockIdx.x, tid = threadIdx.x;
  __shared__ float adj[2500];
  __shared__ float bufA[6400];
  __shared__ float bufB[6400];
  __shared__ float xm[128], hv1[64], raw[80];
  for (int i=tid;i<2500;i+=256) adj[i] = adjg[b*2500+i];

  const int j = tid & 127, nh = tid >> 7;
  float acc[25];
  #pragma unroll
  for (int q=0;q<25;q++) acc[q]=0.f;
  for (int ic=0; ic<4; ic++){
    __syncthreads();
    for (int e=tid; e<800; e+=256){
      int n = e>>4, seg = (e&15)*4;
      *(float4*)&bufB[n*64+seg] = *(const float4*)(h3 + (long)b*12800 + n*256 + ic*64 + seg);
    }
    __syncthreads();
    for (int i=0;i<64;i+=4){
      float w0 = Wc1[(long)(ic*64+i+0)*128 + j];
      float w1 = Wc1[(long)(ic*64+i+1)*128 + j];
      float w2 = Wc1[(long)(ic*64+i+2)*128 + j];
      float w3 = Wc1[(long)(ic*64+i+3)*128 + j];
      #pragma unroll
      for (int q=0;q<25;q++){
        float4 xv = *(const float4*)&bufB[(nh*25+q)*64 + i];
        acc[q] += xv.x*w0 + xv.y*w1 + xv.z*w2 + xv.w*w3;
      }
    }
  }
  __syncthreads();
  #pragma unroll
  for (int q=0;q<25;q++) bufA[(nh*25+q)*128 + j] = acc[q];
  __syncthreads();
  {
    float a2[25];
    float bv = bc1[j];
    #pragma unroll
    for (int q=0;q<25;q++) a2[q]=bv;
    for (int qq=0; qq<50; qq++){
      float hvv = bufA[qq*128 + j];
      #pragma unroll
      for (int q=0;q<25;q++) a2[q] += adj[(nh*25+q)*50 + qq]*hvv;
    }
    __syncthreads();
    #pragma unroll
    for (int q=0;q<25;q++) bufB[(nh*25+q)*128 + j] = lrelu(a2[q]);
  }
  __syncthreads();
  {
    float a2[25];
    #pragma unroll
    for (int q=0;q<25;q++) a2[q]=0.f;
    for (int i=0;i<128;i+=4){
      float w0 = Wc2[(long)(i+0)*128 + j];
      float w1 = Wc2[(long)(i+1)*128 + j];
      float w2 = Wc2[(long)(i+2)*128 + j];
      float w3 = Wc2[(long)(i+3)*128 + j];
      #pragma unroll
      for (int q=0;q<25;q++){
        float4 xv = *(const float4*)&bufB[(nh*25+q)*128 + i];
        a2[q] += xv.x*w0 + xv.y*w1 + xv.z*w2 + xv.w*w3;
      }
    }
    __syncthreads();
    #pragma unroll
    for (int q=0;q<25;q++) bufA[(nh*25+q)*128 + j] = a2[q];
  }
  __syncthreads();
  {
    float a2[25];
    float bv = bc2[j];
    #pragma unroll
    for (int q=0;q<25;q++) a2[q]=bv;
    for (int qq=0; qq<50; qq++){
      float hvv = bufA[qq*128 + j];
      #pragma unroll
      for (int q=0;q<25;q++) a2[q] += adj[(nh*25+q)*50 + qq]*hvv;
    }
    __syncthreads();
    #pragma unroll
    for (int q=0;q<25;q++) bufB[(nh*25+q)*128 + j] = lrelu(a2[q]);
  }
  __syncthreads();
  if (tid < 128){
    float s = 0.f;
    for (int n=0;n<50;n++) s += bufB[n*128 + tid];
    xm[tid] = s * (1.f/50.f);
  }
  __syncthreads();
  if (tid < 64){
    float s = bf1[tid];
    for (int i=0;i<128;i++) s += xm[i]*Wf1[i*64 + tid];
    hv1[tid] = lrelu(s);
  }
  __syncthreads();
  if (tid < 80){
    float s = bf2[tid];
    for (int i=0;i<64;i++) s += hv1[i]*Wf2[i*80 + tid];
    raw[tid] = s;
  }
  __syncthreads();
  if (tid < 4){
    float c = 0.f;
    for (int k=0;k<20;k++){
      c += raw[k*4 + tid];
      hypg[b*80 + k*4 + tid] = maxp[tid] / (1.f + expf(-c));
    }
  }
}

// ---------------- MFMA: t[b,p,m] = sum_n A[p,m,n]*y[b,p,n]; y staged in LDS ----------------
// grid (50,4), 4 waves; wave handles m-tiles (by*4+w) and (by*4+w+16)
__global__ __launch_bounds__(256) void k_g1m(const unsigned short* __restrict__ abf,
                      const unsigned short* __restrict__ ybf, unsigned short* __restrict__ tbf){
  const int p = blockIdx.x;
  const int tid = threadIdx.x, wave = tid>>6, lane = tid&63;
  __shared__ unsigned short ylds[16][1032];
  {
    int b = tid>>4, c0 = (tid&15)*8;
    const unsigned short* yr = ybf + ((long)b*NP + p)*NN;
    #pragma unroll
    for (int it=0; it<8; it++)
      *(uint4*)&ylds[b][it*128 + c0] = *(const uint4*)(yr + it*128 + c0);
  }
  __syncthreads();
  const int lr = lane&15, kg = lane>>4;
  const int mt0 = blockIdx.y*4 + wave;
  const int m0 = mt0*16, m1 = (mt0+16)*16;
  const unsigned short* a0 = abf + ((long)p*NM + m0 + lr)*NN + kg*8;
  const unsigned short* a1 = abf + ((long)p*NM + m1 + lr)*NN + kg*8;
  const unsigned short* yp = &ylds[lr][kg*8];
  f32x4 acc0a={0.f,0.f,0.f,0.f}, acc0b={0.f,0.f,0.f,0.f};
  f32x4 acc1a={0.f,0.f,0.f,0.f}, acc1b={0.f,0.f,0.f,0.f};
  #pragma unroll 4
  for (int ks=0; ks<32; ks+=2){
    bf16x8 y0 = *(const bf16x8*)(yp + ks*32);
    bf16x8 y1 = *(const bf16x8*)(yp + ks*32 + 32);
    bf16x8 a00 = *(const bf16x8*)(a0 + (long)ks*32);
    bf16x8 a01 = *(const bf16x8*)(a0 + (long)ks*32 + 32);
    bf16x8 a10 = *(const bf16x8*)(a1 + (long)ks*32);
    bf16x8 a11 = *(const bf16x8*)(a1 + (long)ks*32 + 32);
    acc0a = __builtin_amdgcn_mfma_f32_16x16x32_bf16(a00, y0, acc0a, 0, 0, 0);
    acc1a = __builtin_amdgcn_mfma_f32_16x16x32_bf16(a10, y0, acc1a, 0, 0, 0);
    acc0b = __builtin_amdgcn_mfma_f32_16x16x32_bf16(a01, y1, acc0b, 0, 0, 0);
    acc1b = __builtin_amdgcn_mfma_f32_16x16x32_bf16(a11, y1, acc1b, 0, 0, 0);
  }
  f32x4 acc0 = acc0a + acc0b;
  f32x4 acc1 = acc1a + acc1b;
  #pragma unroll
  for (int r=0;r<4;r++){
    tbf[((long)lr*NP + p)*NM + m0 + kg*4 + r] = f2bf(acc0[r]);
    tbf[((long)lr*NP + p)*NM + m1 + kg*4 + r] = f2bf(acc1[r]);
  }
}

// ---------------- MFMA: z[b,p,n] = sum_m A[p,m,n]*src[b,p,m]; src staged in LDS ----------------
// grid (50,8), 4 waves; wave handles n-tiles (by*4+w) and (by*4+w+32)
template<bool BF16IN>
__global__ __launch_bounds__(256) void k_gatm(const unsigned short* __restrict__ abfT,
                      const void* __restrict__ srcv, float* __restrict__ z){
  const int p = blockIdx.x;
  const int tid = threadIdx.x, wave = tid>>6, lane = tid&63;
  __shared__ unsigned short tlds[16][520];
  {
    int b = tid>>4, c0 = (tid&15)*8;
    if constexpr (BF16IN){
      const unsigned short* tr = (const unsigned short*)srcv + ((long)b*NP + p)*NM;
      #pragma unroll
      for (int it=0; it<4; it++)
        *(uint4*)&tlds[b][it*128 + c0] = *(const uint4*)(tr + it*128 + c0);
    } else {
      const float* tr = (const float*)srcv + ((long)b*NP + p)*NM;
      #pragma unroll
      for (int it=0; it<4; it++){
        float4 lo = *(const float4*)(tr + it*128 + c0);
        float4 hi = *(const float4*)(tr + it*128 + c0 + 4);
        unsigned short w[8];
        w[0]=f2bf(lo.x); w[1]=f2bf(lo.y); w[2]=f2bf(lo.z); w[3]=f2bf(lo.w);
        w[4]=f2bf(hi.x); w[5]=f2bf(hi.y); w[6]=f2bf(hi.z); w[7]=f2bf(hi.w);
        *(uint4*)&tlds[b][it*128 + c0] = *(const uint4*)w;
      }
    }
  }
  __syncthreads();
  const int lr = lane&15, kg = lane>>4;
  const int nt0 = blockIdx.y*4 + wave;
  const int n0 = nt0*16, n1 = (nt0+32)*16;
  const unsigned short* b0 = abfT + ((long)p*NN + n0 + lr)*NM + kg*8;
  const unsigned short* b1 = abfT + ((long)p*NN + n1 + lr)*NM + kg*8;
  const unsigned short* tp = &tlds[lr][kg*8];
  f32x4 acc0a={0.f,0.f,0.f,0.f}, acc0b={0.f,0.f,0.f,0.f};
  f32x4 acc1a={0.f,0.f,0.f,0.f}, acc1b={0.f,0.f,0.f,0.f};
  #pragma unroll 4
  for (int ks=0; ks<16; ks+=2){
    bf16x8 t0 = *(const bf16x8*)(tp + ks*32);
    bf16x8 t1 = *(const bf16x8*)(tp + ks*32 + 32);
    bf16x8 b00 = *(const bf16x8*)(b0 + (long)ks*32);
    bf16x8 b01 = *(const bf16x8*)(b0 + (long)ks*32 + 32);
    bf16x8 b10 = *(const bf16x8*)(b1 + (long)ks*32);
    bf16x8 b11 = *(const bf16x8*)(b1 + (long)ks*32 + 32);
    acc0a = __builtin_amdgcn_mfma_f32_16x16x32_bf16(t0, b00, acc0a, 0, 0, 0);
    acc1a = __builtin_amdgcn_mfma_f32_16x16x32_bf16(t0, b10, acc1a, 0, 0, 0);
    acc0b = __builtin_amdgcn_mfma_f32_16x16x32_bf16(t1, b01, acc0b, 0, 0, 0);
    acc1b = __builtin_amdgcn_mfma_f32_16x16x32_bf16(t1, b11, acc1b, 0, 0, 0);
  }
  f32x4 acc0 = acc0a + acc0b;
  f32x4 acc1 = acc1a + acc1b;
  #pragma unroll
  for (int r=0;r<4;r++){
    int bb = kg*4 + r;
    z[((long)bb*NP + p)*NN + n0 + lr] = acc0[r];
    z[((long)bb*NP + p)*NN + n1 + lr] = acc1[r];
  }
}

// ---------------- fused scan update ----------------
__global__ __launch_bounds__(256) void k_upd(const float* __restrict__ zz, const float* __restrict__ atb,
                      const float* __restrict__ dmg, const float* __restrict__ snbg,
                      const float* __restrict__ hypg, int k,
                      float* __restrict__ y, unsigned short* __restrict__ ybf,
                      float* __restrict__ u, float* __restrict__ dl,
                      float* __restrict__ yout){
  const int b = blockIdx.x;
  const int n0 = blockIdx.y*128;
  const int tid = threadIdx.x;
  __shared__ float yn[50][128];
  __shared__ float dms[2500];
  __shared__ float sa[4];
  if (tid<4) sa[tid] = hypg[b*80 + k*4 + tid];
  for (int i=tid;i<2500;i+=256) dms[i] = dmg[b*2500+i];
  __syncthreads();
  const float alpha = sa[0], tau = sa[1], rho = sa[2], eta = sa[3];
  for (int e=tid; e<6400; e+=256){
    const int p = e>>7, nn = e&127;
    const long idx = ((long)b*NP + p)*NN + n0 + nn;
    float yv = y[idx];
    float g = zz[idx] - atb[idx]
            + ((yv>0.f)?1.f:((yv<0.f)?-1.f:0.f))*tau
            + u[idx]*snbg[b*NP+p] + dl[idx]*rho;
    float ynv = yv - alpha*g;
    yn[p][nn] = ynv;
    y[idx] = ynv;
    ybf[idx] = f2bf(ynv);
    yout[(long)k*YSZ + idx] = ynv;
  }
  __syncthreads();
  for (int e=tid; e<6400; e+=256){
    const int p = e>>7, nn = e&127;
    float s = 0.f;
    #pragma unroll 10
    for (int q=0;q<NP;q++) s += dms[p*50+q]*yn[q][nn];
    const long idx = ((long)b*NP + p)*NN + n0 + nn;
    dl[idx] = s;
    u[idx] += s*eta;
  }
}

extern "C" void kernel_launch(void* const* d_in, const int* in_sizes, int n_in,
                              void* d_out, int out_size, void* d_ws, size_t ws_size,
                              hipStream_t stream){
  (void)in_sizes; (void)n_in; (void)out_size; (void)ws_size;
  const float* bin = (const float*)d_in[0];
  const float* A   = (const float*)d_in[1];
  const int*   ei  = (const int*)d_in[2];
  const float* mxp = (const float*)d_in[3];
  const float* We1 = (const float*)d_in[4];  const float* be1 = (const float*)d_in[5];
  const float* We2 = (const float*)d_in[6];  const float* be2 = (const float*)d_in[7];
  const float* We3 = (const float*)d_in[8];  const float* be3 = (const float*)d_in[9];
  const float* Wc1 = (const float*)d_in[10]; const float* bc1 = (const float*)d_in[11];
  const float* Wc2 = (const float*)d_in[12]; const float* bc2 = (const float*)d_in[13];
  const float* Wf1 = (const float*)d_in[14]; const float* bf1 = (const float*)d_in[15];
  const float* Wf2 = (const float*)d_in[16]; const float* bf2 = (const float*)d_in[17];
  const float* y0  = (const float*)d_in[18];
  const float* u0  = (const float*)d_in[19];
  const float* dd0 = (const float*)d_in[20];
  float* out = (float*)d_out;

  char* cur = (char*)d_ws;
  auto alloc = [&](size_t bytes)->void*{
    void* pp = (void*)cur; cur += (bytes + 255) & ~(size_t)255; return pp;
  };
  unsigned short* abf  = (unsigned short*)alloc(ASZ*2);   // 52.4 MB
  unsigned short* abfT = (unsigned short*)alloc(ASZ*2);   // 52.4 MB
  float* atb = (float*)alloc(YSZ*4);
  float* y   = (float*)alloc(YSZ*4);
  unsigned short* ybf = (unsigned short*)alloc(YSZ*2);
  float* u   = (float*)alloc(YSZ*4);
  float* dl  = (float*)alloc(YSZ*4);
  unsigned short* tbf = (unsigned short*)alloc((size_t)NB*NP*NM*2);
  float* z   = (float*)alloc(YSZ*4);
  float* h1  = (float*)alloc((size_t)16*3200*4);
  float* h2  = (float*)alloc((size_t)16*6400*4);
  float* h3  = (float*)alloc((size_t)16*12800*4);
  float* adj = (float*)alloc((size_t)16*2500*4);
  float* dm  = (float*)alloc((size_t)16*2500*4);
  float* snb = (float*)alloc((size_t)16*50*4);
  float* hyp = (float*)alloc((size_t)16*80*4);
  float* part= (float*)alloc((size_t)21000000);   // max 25*16*12800*4 = 20.5 MB

  // ---- one-time prep ----
  k_prep<<<dim3(50,8,16), dim3(256), 0, stream>>>(A, abf, abfT);
  k_init<<<dim3(800), dim3(256), 0, stream>>>(y0, u0, dd0, y, u, dl, ybf, (int)YSZ);
  k_gatm<false><<<dim3(50,8), dim3(256), 0, stream>>>(abfT, bin, atb);   // Atb = A^T b

  // ---- encoder MLP ----
  k_enc2<<<dim3(4,50),  dim3(256), 0, stream>>>(bin, We1, part, 25600, 3200, 512, 0);
  k_enc_reduce<<<dim3(200), dim3(256), 0, stream>>>(part, be1, h1, 3200, 50);
  k_enc2<<<dim3(7,25),  dim3(256), 0, stream>>>(h1, We2, part, 3200, 6400, 128, 1);
  k_enc_reduce<<<dim3(400), dim3(256), 0, stream>>>(part, be2, h2, 6400, 25);
  k_enc2<<<dim3(13,25), dim3(256), 0, stream>>>(h2, We3, part, 6400, 12800, 256, 1);
  k_enc_reduce<<<dim3(800), dim3(256), 0, stream>>>(part, be3, h3, 12800, 25);

  // ---- graph + fused GNN/head ----
  k_graph<<<dim3(16), dim3(64), 0, stream>>>(ei, adj, dm, snb);
  k_gnn<<<dim3(16), dim3(256), 0, stream>>>(h3, Wc1, bc1, Wc2, bc2, Wf1, bf1, Wf2, bf2, mxp, adj, hyp);

  // ---- scan ----
  for (int k=0;k<NK;k++){
    k_g1m<<<dim3(50,4),  dim3(256), 0, stream>>>(abf, ybf, tbf);
    k_gatm<true><<<dim3(50,8), dim3(256), 0, stream>>>(abfT, tbf, z);
    k_upd<<<dim3(16,8),  dim3(256), 0, stream>>>(z, atb, dm, snb, hyp, k, y, ybf, u, dl, out);
  }
}